// Round 5
// baseline (626.073 us; speedup 1.0000x reference)
//
#include <hip/hip_runtime.h>
#include <hip/hip_bf16.h>

// RGCN 3-layer forward on MI355X — R9: B-direct + reg-staged-A GEMM.
//   R4-R8 invariant traced to LDS-pipe appetite (~35 us/CU) + barrier-coupled
//   staging. Changes vs R8 (GEMM only, rest verbatim):
//   (a) weight fragments (0.9 MB matrix, L2-hot) loaded DIRECTLY global->VGPR,
//       ping-pong prefetched 1 K-tile ahead: no B LDS staging, half the
//       ds_reads, B path fully decoupled from barriers.
//   (b) node rows reg-staged (global->reg->ds_write, T14): ALL VMEM is
//       compiler-tracked, no manual vmcnt ledger; per-iter barrier is
//       lgkmcnt(0)+s_barrier ONLY, so global loads stay in flight across it
//       (structural fix for the m97 vmcnt(0)-drain).
//   A ping-pong 2x8 KB LDS. BM=BN=128, BK=32, 36 K-tiles, 4 waves (2Mx2N,
//   64x64 wave-tile), chunk swizzle cs^((row>>1)&3) (0 conflicts measured),
//   operand-swapped packed epilogue w/ fused bias+ReLU, bijective XCD remap.

#define D 384
#define KC 1152      // concat K = 3*D
#define BM 128       // nodes per block
#define BN 128       // out cols per block
#define BK 32
#define NKT (KC / BK)  // 36 K-tiles
#define NTN (D / BN)   // 3 N-tiles

typedef __attribute__((ext_vector_type(8))) short short8;
typedef __attribute__((ext_vector_type(4))) float floatx4;
typedef unsigned int uint;
typedef unsigned short ushort;

#define LGKM0_BAR() asm volatile("s_waitcnt lgkmcnt(0)\n\ts_barrier" ::: "memory")

__device__ __forceinline__ ushort f2bf(float x) {
    __hip_bfloat16 h = __float2bfloat16(x);
    return *reinterpret_cast<ushort*>(&h);
}

__device__ __forceinline__ uint pack2(float a, float b) {
    return (uint)f2bf(a) | ((uint)f2bf(b) << 16);
}

// ---- fused GEMM: H[M,D] = [X|AG] @ BT^T + bias (+relu) ----
// X: [M,384] bf16 (K 0..383), AG: [M,768] bf16 (K 384..1151),
// BT: [384 n-rows][1152 k] bf16. Output: Xn bf16 [M,384] or outf f32 [M,384].
__global__ __launch_bounds__(256, 3) void gemm_fused(
    const ushort* __restrict__ X, const ushort* __restrict__ AG,
    const ushort* __restrict__ BT, const float* __restrict__ bias,
    ushort* __restrict__ Xn, float* __restrict__ outf,
    int M, int nwg, int relu)
{
    __shared__ alignas(16) ushort As0[BM * BK];   // node rows, ping
    __shared__ alignas(16) ushort As1[BM * BK];   // node rows, pong

    // bijective XCD-aware remap (m204): contiguous wg range per XCD;
    // 3 N-tiles of an M-tile consecutive -> A-panel L2 reuse.
    const int o = blockIdx.x;
    const int xcd = o & 7, lid = o >> 3;
    const int q = nwg >> 3, r = nwg & 7;
    const int wg = (xcd < r ? xcd * (q + 1) : r * (q + 1) + (xcd - r) * q) + lid;
    const int bnt = wg % NTN, bmt = wg / NTN;
    const int bm = bmt * BM, bn = bnt * BN;

    const int tid = threadIdx.x;
    const int wave = tid >> 6, lane = tid & 63;
    const int wm = wave >> 1;      // m-half 0..1 (64 nodes each)
    const int wn = wave & 1;       // n-half 0..1 (64 cols each)
    const int l15 = lane & 15, k8 = lane >> 4;

    floatx4 acc[4][4] = {};        // acc[nf][mf]: D[wcol][node]

    // per-thread A-stage geometry: 2 chunks of 16 B (128 rows x 64 B = 512)
    // LDS slot (row, cs) <- global chunk (row, gc = cs ^ ((row>>1)&3))
    int agr[2], agc[2];
#pragma unroll
    for (int jj = 0; jj < 2; ++jj) {
        const int ch = jj * 256 + tid;
        const int row = ch >> 2, cs = ch & 3;
        agc[jj] = cs ^ ((row >> 1) & 3);
        agr[jj] = min(bm + row, M - 1);
    }

    // load A-slab (K-tile kt) into regs: 2 x global_load_dwordx4 / thread
    auto aglob = [&](int kt, short8* ar) {
#pragma unroll
        for (int jj = 0; jj < 2; ++jj) {
            const ushort* p = (kt < 12)
                ? X + (size_t)agr[jj] * 384 + kt * BK
                : AG + (size_t)agr[jj] * 768 + (kt - 12) * BK;
            ar[jj] = *(const short8*)(p + agc[jj] * 8);
        }
    };
    // write staged regs to LDS (linear slots): 2 x ds_write_b128 / thread
    auto awrite = [&](ushort* Asb, const short8* ar) {
#pragma unroll
        for (int jj = 0; jj < 2; ++jj)
            *(short8*)(Asb + (size_t)(jj * 256 + tid) * 8) = ar[jj];
    };
    // direct-load 4 weight fragments for K-tile kt (L2-hot, 16 lines/instr)
    auto bload = [&](int kt, short8* af) {
#pragma unroll
        for (int nf = 0; nf < 4; ++nf) {
            const int rr = bn + wn * 64 + nf * 16 + l15;
            af[nf] = *(const short8*)(BT + (size_t)rr * KC + kt * BK + k8 * 8);
        }
    };
    // read 4 node fragments from LDS (swizzled)
    auto aread = [&](const ushort* Asb, short8* bf) {
#pragma unroll
        for (int mf = 0; mf < 4; ++mf) {
            const int rr = wm * 64 + mf * 16 + l15;
            bf[mf] = *(const short8*)(Asb + rr * BK + ((k8 ^ ((rr >> 1) & 3)) << 3));
        }
    };

    short8 afA[4], afB[4];   // weight-frag ping-pong (tile j / j+1)
    short8 arA[2], arB[2];   // A-stage ping-pong

    // prologue: A(0)->regs->LDS ping; A(1)->regs; B(0)->regs
    aglob(0, arA);
    bload(0, afA);
    aglob(1, arB);
    awrite(As0, arA);        // compiler waits arA's vmcnt, leaves rest in flight
    LGKM0_BAR();

    for (int j = 0; j < NKT; j += 2) {
        {   // even tile j: LDS=As0, weights=afA
            short8 bf[4];
            aread(As0, bf);
            if (j + 2 < NKT) aglob(j + 2, arA);
            bload(j + 1, afB);
            __builtin_amdgcn_s_setprio(1);
#pragma unroll
            for (int nf = 0; nf < 4; ++nf)
#pragma unroll
                for (int mf = 0; mf < 4; ++mf)
                    acc[nf][mf] = __builtin_amdgcn_mfma_f32_16x16x32_bf16(
                        afA[nf], bf[mf], acc[nf][mf], 0, 0, 0);
            __builtin_amdgcn_s_setprio(0);
            awrite(As1, arB);            // tile j+1 -> pong
            LGKM0_BAR();
        }
        {   // odd tile j+1: LDS=As1, weights=afB
            short8 bf[4];
            aread(As1, bf);
            if (j + 3 < NKT) aglob(j + 3, arB);
            if (j + 2 < NKT) bload(j + 2, afA);
            __builtin_amdgcn_s_setprio(1);
#pragma unroll
            for (int nf = 0; nf < 4; ++nf)
#pragma unroll
                for (int mf = 0; mf < 4; ++mf)
                    acc[nf][mf] = __builtin_amdgcn_mfma_f32_16x16x32_bf16(
                        afB[nf], bf[mf], acc[nf][mf], 0, 0, 0);
            __builtin_amdgcn_s_setprio(0);
            if (j + 2 < NKT) awrite(As0, arA);   // tile j+2 -> ping
            LGKM0_BAR();
        }
    }

    // epilogue (R8-verified): lane (k8,l15) of frag (nf,mf) holds out-cols
    // bn + wn*64 + nf*16 + k8*4 + {0..3} of node bm + wm*64 + mf*16 + l15
    const int node0 = bm + wm * 64 + l15;
    const int colg = bn + wn * 64 + k8 * 4;
    float4 bv[4];
#pragma unroll
    for (int nf = 0; nf < 4; ++nf)
        bv[nf] = *(const float4*)(bias + colg + nf * 16);

#pragma unroll
    for (int mf = 0; mf < 4; ++mf) {
        const int node = node0 + mf * 16;
        if (node < M) {
            float v[4][4];
#pragma unroll
            for (int nf = 0; nf < 4; ++nf) {
                v[nf][0] = acc[nf][mf][0] + bv[nf].x;
                v[nf][1] = acc[nf][mf][1] + bv[nf].y;
                v[nf][2] = acc[nf][mf][2] + bv[nf].z;
                v[nf][3] = acc[nf][mf][3] + bv[nf].w;
                if (relu) {
#pragma unroll
                    for (int t = 0; t < 4; ++t) v[nf][t] = fmaxf(v[nf][t], 0.f);
                }
            }
            if (Xn) {
                uint2* rowp = (uint2*)(Xn + (size_t)node * D + colg);
#pragma unroll
                for (int nf = 0; nf < 4; ++nf) {
                    uint2 o2;
                    o2.x = pack2(v[nf][0], v[nf][1]);
                    o2.y = pack2(v[nf][2], v[nf][3]);
                    rowp[nf * 4] = o2;         // nf*16 cols = 4 uint2
                }
            } else {
                float4* rowp = (float4*)(outf + (size_t)node * D + colg);
#pragma unroll
                for (int nf = 0; nf < 4; ++nf)
                    rowp[nf * 4] = make_float4(v[nf][0], v[nf][1],
                                               v[nf][2], v[nf][3]);
            }
        }
    }
}

// ---- preprocessing: CSR by (rel, dst) ----

__global__ __launch_bounds__(256) void count_edges(
    const int* __restrict__ dst, const int* __restrict__ et,
    int* __restrict__ cntI, int E, int M)
{
    const int e = blockIdx.x * blockDim.x + threadIdx.x;
    if (e < E) atomicAdd(&cntI[(size_t)et[e] * M + dst[e]], 1);
}

__global__ __launch_bounds__(256) void finalize_cnt(
    const int* __restrict__ cntI, float* __restrict__ invc, int n)
{
    const int i = blockIdx.x * blockDim.x + threadIdx.x;
    if (i < n) invc[i] = 1.0f / (float)max(cntI[i], 1);
}

// ---- 3-kernel hierarchical exclusive scan (n ~ 100k) ----
__global__ __launch_bounds__(1024) void scan_local(
    const int* __restrict__ hist, int* __restrict__ offs,
    int* __restrict__ bsums, int n)
{
    __shared__ int tmp[1024];
    const int tid = threadIdx.x;
    const int i = blockIdx.x * 1024 + tid;
    const int v = (i < n) ? hist[i] : 0;
    tmp[tid] = v;
    __syncthreads();
#pragma unroll
    for (int off = 1; off < 1024; off <<= 1) {
        const int add = (tid >= off) ? tmp[tid - off] : 0;
        __syncthreads();
        tmp[tid] += add;
        __syncthreads();
    }
    if (i < n) offs[i] = tmp[tid] - v;
    if (tid == 1023) bsums[blockIdx.x] = tmp[1023];
}

__global__ __launch_bounds__(1024) void scan_bsums(
    int* __restrict__ bsums, int* __restrict__ total_out, int nb)
{
    __shared__ int tmp[1024];
    const int tid = threadIdx.x;
    const int v = (tid < nb) ? bsums[tid] : 0;
    tmp[tid] = v;
    __syncthreads();
#pragma unroll
    for (int off = 1; off < 1024; off <<= 1) {
        const int add = (tid >= off) ? tmp[tid - off] : 0;
        __syncthreads();
        tmp[tid] += add;
        __syncthreads();
    }
    if (tid < nb) bsums[tid] = tmp[tid] - v;
    if (tid == 1023) *total_out = tmp[1023];
}

__global__ __launch_bounds__(1024) void scan_add(
    int* __restrict__ offs, const int* __restrict__ bsums, int n)
{
    const int i = blockIdx.x * 1024 + threadIdx.x;
    if (i < n) offs[i] += bsums[blockIdx.x];
}

__global__ __launch_bounds__(256) void fill_sorted(
    const int* __restrict__ src, const int* __restrict__ dst,
    const int* __restrict__ et, const int* __restrict__ offs,
    int* __restrict__ cursor, int* __restrict__ sorted, int E, int M)
{
    const int e = blockIdx.x * blockDim.x + threadIdx.x;
    if (e < E) {
        const int key = et[e] * M + dst[e];
        const int pos = offs[key] + atomicAdd(&cursor[key], 1);
        sorted[pos] = src[e];
    }
}

// ---- weights -> BT bf16 [384 n-rows][1152 k-cols] per layer ----
// BT[n][k] = Wcat[k][n]; k<384: root, k<768: W[0], else W[1].
__global__ __launch_bounds__(256) void build_bt(
    const float* __restrict__ root1, const float* __restrict__ W1,
    const float* __restrict__ root2, const float* __restrict__ W2,
    const float* __restrict__ root3, const float* __restrict__ W3,
    ushort* __restrict__ BT)
{
    __shared__ float tile[32][33];
    const int l = blockIdx.z;
    const float* root = (l == 0) ? root1 : (l == 1) ? root2 : root3;
    const float* W    = (l == 0) ? W1    : (l == 1) ? W2    : W3;
    const int k0 = blockIdx.x * 32;   // K block (0..1151)
    const int n0 = blockIdx.y * 32;   // N block (0..383)
    const int tx = threadIdx.x & 31;
    const int ty = threadIdx.x >> 5;
    const float* srcm;
    int koff;
    if (k0 < D)          { srcm = root;      koff = 0; }
    else if (k0 < 2 * D) { srcm = W;         koff = D; }
    else                 { srcm = W + D * D; koff = 2 * D; }
#pragma unroll
    for (int i = 0; i < 4; ++i) {
        const int k = k0 - koff + ty + i * 8;
        tile[ty + i * 8][tx] = srcm[(size_t)k * D + n0 + tx];
    }
    __syncthreads();
    ushort* dst = BT + (size_t)l * D * KC;
#pragma unroll
    for (int i = 0; i < 4; ++i) {
        const int nn = n0 + ty + i * 8;
        const int kk = k0 + tx;
        dst[(size_t)nn * KC + kk] = f2bf(tile[tx][ty + i * 8]);
    }
}

__global__ __launch_bounds__(256) void cast_f32_to_bf16(
    const float* __restrict__ x, ushort* __restrict__ y, int n4)
{
    const int i = blockIdx.x * blockDim.x + threadIdx.x;
    if (i < n4) {
        const float4 v = ((const float4*)x)[i];
        uint2 o;
        o.x = pack2(v.x, v.y);
        o.y = pack2(v.z, v.w);
        ((uint2*)y)[i] = o;
    }
}

// ---- relation aggregation: one wave per node, mean over in-edges per rel ----
// Reads X [M,384] bf16 rows of sources; writes AG[d][r*384 + :] bf16.
__global__ __launch_bounds__(256) void aggregate_rel(
    const ushort* __restrict__ X, const int* __restrict__ sorted,
    const int* __restrict__ offs, const float* __restrict__ invc,
    ushort* __restrict__ AG, int M)
{
    const int wave = threadIdx.x >> 6;
    const int lane = threadIdx.x & 63;
    const int d = blockIdx.x * 4 + wave;
    if (d >= M) return;

#pragma unroll
    for (int r = 0; r < 2; ++r) {
        const int key = r * M + d;
        const int beg = offs[key], end = offs[key + 1];
        float g[6] = {0.f, 0.f, 0.f, 0.f, 0.f, 0.f};
        for (int i = beg; i < end; ++i) {
            const int s = sorted[i];
            const uint* tp = (const uint*)(X + (size_t)s * D);
#pragma unroll
            for (int p = 0; p < 3; ++p) {
                const uint b = tp[lane + 64 * p];
                g[2 * p]     += __uint_as_float(b << 16);
                g[2 * p + 1] += __uint_as_float(b & 0xffff0000u);
            }
        }
        const float ic = invc[key];
        uint* op = (uint*)(AG + (size_t)d * (2 * D) + r * D);
#pragma unroll
        for (int p = 0; p < 3; ++p)
            op[lane + 64 * p] = pack2(ic * g[2 * p], ic * g[2 * p + 1]);
    }
}

extern "C" void kernel_launch(void* const* d_in, const int* in_sizes, int n_in,
                              void* d_out, int out_size, void* d_ws, size_t ws_size,
                              hipStream_t stream)
{
    const float* emb   = (const float*)d_in[0];
    const int*   eidx  = (const int*)d_in[1];
    const int*   et    = (const int*)d_in[2];
    const float* W1    = (const float*)d_in[3];
    const float* root1 = (const float*)d_in[4];
    const float* bias1 = (const float*)d_in[5];
    const float* W2    = (const float*)d_in[6];
    const float* root2 = (const float*)d_in[7];
    const float* bias2 = (const float*)d_in[8];
    const float* W3    = (const float*)d_in[9];
    const float* root3 = (const float*)d_in[10];
    const float* bias3 = (const float*)d_in[11];

    float* out = (float*)d_out;
    const int M = in_sizes[0] / D;   // 50000
    const int E = in_sizes[1] / 2;   // 200000
    const int* src  = eidx;
    const int* dstv = eidx + E;

    const int n = 2 * M;
    const int nb = (n + 1023) / 1024;

    // Workspace: Xa[M*384]bf16 | Xb2[M*384]bf16 | AG[M*768]bf16 |
    //            BT[3*384*1152]bf16 | invcnt[2M]f32 | cntI[2M]i32 |
    //            offs[2M+1]i32 | sorted[E]i32 | bsums[nb]i32   (~158 MB)
    char* w = (char*)d_ws;
    ushort* Xa  = (ushort*)w;         w += (size_t)M * D * 2;
    ushort* Xb2 = (ushort*)w;         w += (size_t)M * D * 2;
    ushort* AG  = (ushort*)w;         w += (size_t)M * 2 * D * 2;
    ushort* BT  = (ushort*)w;         w += (size_t)3 * D * KC * 2;
    float* invcnt = (float*)w;        w += (size_t)n * 4;
    int* cntI = (int*)w;              w += (size_t)n * 4;
    int* offs = (int*)w;              w += ((size_t)n + 1) * 4;
    int* sorted = (int*)w;            w += (size_t)E * 4;
    int* bsums = (int*)w;

    // --- preprocessing ---
    hipMemsetAsync(cntI, 0, (size_t)n * sizeof(int), stream);
    count_edges<<<(E + 255) / 256, 256, 0, stream>>>(dstv, et, cntI, E, M);
    finalize_cnt<<<(n + 255) / 256, 256, 0, stream>>>(cntI, invcnt, n);
    scan_local<<<nb, 1024, 0, stream>>>(cntI, offs, bsums, n);
    scan_bsums<<<1, 1024, 0, stream>>>(bsums, offs + n, nb);
    scan_add<<<nb, 1024, 0, stream>>>(offs, bsums, n);
    hipMemsetAsync(cntI, 0, (size_t)n * sizeof(int), stream);
    fill_sorted<<<(E + 255) / 256, 256, 0, stream>>>(src, dstv, et, offs, cntI, sorted, E, M);

    build_bt<<<dim3(KC / 32, D / 32, 3), 256, 0, stream>>>(root1, W1, root2, W2, root3, W3, BT);
    cast_f32_to_bf16<<<(M * D / 4 + 255) / 256, 256, 0, stream>>>(emb, Xa, M * D / 4);

    // GEMM grid: 391 M-tiles x 3 N-tiles, bijective XCD swizzle in-kernel
    const int Mtiles = (M + BM - 1) / BM;
    const int nwg = Mtiles * NTN;
    const int agg_blocks = (M + 3) / 4;

    // Layer 1: X = Xa -> Xb2
    aggregate_rel<<<agg_blocks, 256, 0, stream>>>(Xa, sorted, offs, invcnt, AG, M);
    gemm_fused<<<nwg, 256, 0, stream>>>(Xa, AG, BT, bias1, Xb2, nullptr, M, nwg, 1);
    // Layer 2: Xb2 -> Xa
    aggregate_rel<<<agg_blocks, 256, 0, stream>>>(Xb2, sorted, offs, invcnt, AG, M);
    gemm_fused<<<nwg, 256, 0, stream>>>(Xb2, AG, BT + (size_t)D * KC, bias2, Xa, nullptr, M, nwg, 1);
    // Layer 3: Xa -> out (f32, no relu)
    aggregate_rel<<<agg_blocks, 256, 0, stream>>>(Xa, sorted, offs, invcnt, AG, M);
    gemm_fused<<<nwg, 256, 0, stream>>>(Xa, AG, BT + (size_t)2 * D * KC, bias3, nullptr, out, M, nwg, 0);
}

// Round 6
// 472.811 us; speedup vs baseline: 1.3242x; 1.3242x over previous
//
#include <hip/hip_runtime.h>
#include <hip/hip_bf16.h>

// RGCN 3-layer forward on MI355X — R10: R8 GEMM (best measured, 71 us) +
//   parallelized aggregation.
//   GEMM verdict after R5-R9: five structurally distinct schedules land at
//   71-120 us; R8 (LDS ring, counted vmcnt, 3 blocks/CU) is best and its dur
//   is invariant to traffic -> locally converged, restored verbatim.
//   New focus: 3*agg + preproc ~ 272 us > 3*GEMM (215 us).
//   (a) aggregate_rel: one wave per (node,rel) [2x waves], lane-parallel
//       edge-index load + __shfl broadcast (1 coalesced load / 64 edges
//       instead of a serial uniform load per edge), gather unrolled x2.
//   (b) finalize_cnt folded into scan_local (also self-zeroes cntI) ->
//       2 fewer dispatches, one less memset.

#define D 384
#define KC 1152      // concat K = 3*D
#define BM 128       // nodes per block
#define BN 128       // out cols per block
#define BK 32
#define NKT (KC / BK)  // 36 K-tiles
#define NTN (D / BN)   // 3 N-tiles

typedef __attribute__((ext_vector_type(8))) short short8;
typedef __attribute__((ext_vector_type(4))) float floatx4;
typedef unsigned int uint;
typedef unsigned short ushort;

#define BAR() asm volatile("s_barrier" ::: "memory")
#define WAIT_VM4() asm volatile("s_waitcnt vmcnt(4)" ::: "memory")
#define WAIT_VM0() asm volatile("s_waitcnt vmcnt(0)" ::: "memory")

__device__ __forceinline__ void load_lds16(const void* g, void* l) {
    __builtin_amdgcn_global_load_lds(
        (const __attribute__((address_space(1))) void*)g,
        (__attribute__((address_space(3))) void*)l, 16, 0, 0);
}

__device__ __forceinline__ ushort f2bf(float x) {
    __hip_bfloat16 h = __float2bfloat16(x);
    return *reinterpret_cast<ushort*>(&h);
}

__device__ __forceinline__ uint pack2(float a, float b) {
    return (uint)f2bf(a) | ((uint)f2bf(b) << 16);
}

// Stage one 128x32 bf16 slab (8 KB) = 2 x global_load_lds_dwordx4 / thread
// (256 threads). LDS chunk (row, cs) <- global chunk (row, cs ^ ((row>>1)&3)).
__device__ __forceinline__ void stage_rows(const ushort* __restrict__ g,
                                           size_t stride, int koff,
                                           ushort* l, int grow0, int rmax,
                                           int tid)
{
#pragma unroll
    for (int j = 0; j < 2; ++j) {
        const int ch = j * 256 + tid;          // 0..511
        const int row = ch >> 2;               // 0..127
        const int cs = ch & 3;                 // slot chunk in 64 B row
        const int gc = cs ^ ((row >> 1) & 3);  // global chunk
        const int gr = min(grow0 + row, rmax); // clamp partial tile
        load_lds16(g + (size_t)gr * stride + koff + gc * 8, l + (size_t)ch * 8);
    }
}

// ---- fused GEMM: H[M,D] = [X|AG] @ BT^T + bias (+relu) ----  [R8 verbatim]
// X: [M,384] bf16 (K 0..383), AG: [M,768] bf16 (K 384..1151),
// BT: [384 rows][1152 K] bf16. Output: Xn bf16 [M,384] or outf f32 [M,384].
__global__ __launch_bounds__(256, 3) void gemm_fused(
    const ushort* __restrict__ X, const ushort* __restrict__ AG,
    const ushort* __restrict__ BT, const float* __restrict__ bias,
    ushort* __restrict__ Xn, float* __restrict__ outf,
    int M, int nwg, int relu)
{
    __shared__ alignas(16) ushort As[3][BM * BK];   // node rows,   24 KB ring
    __shared__ alignas(16) ushort Bs[3][BN * BK];   // weight rows, 24 KB ring

    // bijective XCD-aware remap (m204): contiguous wg range per XCD;
    // 3 N-tiles of an M-tile consecutive -> A-panel L2 reuse.
    const int o = blockIdx.x;
    const int xcd = o & 7, lid = o >> 3;
    const int q = nwg >> 3, r = nwg & 7;
    const int wg = (xcd < r ? xcd * (q + 1) : r * (q + 1) + (xcd - r) * q) + lid;
    const int bnt = wg % NTN, bmt = wg / NTN;
    const int bm = bmt * BM, bn = bnt * BN;

    const int tid = threadIdx.x;
    const int wave = tid >> 6, lane = tid & 63;
    const int wm = wave >> 1;      // m-half 0..1 (64 nodes each)
    const int wn = wave & 1;       // n-half 0..1 (64 cols each)
    const int l15 = lane & 15, k8 = lane >> 4;

    floatx4 acc[4][4] = {};        // acc[nf][mf]: D[wcol][node]

    // A-side source select for K-tile kt (block-uniform)
    auto stage_a = [&](int kt, ushort* dst) {
        if (kt < 12) stage_rows(X, 384, kt * BK, dst, bm, M - 1, tid);
        else         stage_rows(AG, 768, (kt - 12) * BK, dst, bm, M - 1, tid);
    };

    // prologue: stage K-tiles 0,1 (8 loads/thread); wait kt0 landed
    stage_a(0, As[0]);
    stage_rows(BT, KC, 0, Bs[0], bn, D - 1, tid);
    stage_a(1, As[1]);
    stage_rows(BT, KC, BK, Bs[1], bn, D - 1, tid);
    WAIT_VM4();
    BAR();

    for (int j = 0; j < NKT; ++j) {
        const ushort* Ab = As[j % 3];
        const ushort* Bb = Bs[j % 3];

        short8 af[4], bf[4];
#pragma unroll
        for (int nf = 0; nf < 4; ++nf) {       // A-operand = weight rows
            const int rr = wn * 64 + nf * 16 + l15;
            af[nf] = *(const short8*)(Bb + rr * BK + ((k8 ^ ((rr >> 1) & 3)) << 3));
        }
#pragma unroll
        for (int mf = 0; mf < 4; ++mf) {       // B-operand = node rows
            const int rr = wm * 64 + mf * 16 + l15;
            bf[mf] = *(const short8*)(Ab + rr * BK + ((k8 ^ ((rr >> 1) & 3)) << 3));
        }

        const int js = j + 2;
        if (js < NKT) {                        // slot of tile j-1 (read done)
            stage_a(js, As[js % 3]);
            stage_rows(BT, KC, js * BK, Bs[js % 3], bn, D - 1, tid);
        }

        __builtin_amdgcn_s_setprio(1);
#pragma unroll
        for (int nf = 0; nf < 4; ++nf)
#pragma unroll
            for (int mf = 0; mf < 4; ++mf)
                acc[nf][mf] = __builtin_amdgcn_mfma_f32_16x16x32_bf16(
                    af[nf], bf[mf], acc[nf][mf], 0, 0, 0);
        __builtin_amdgcn_s_setprio(0);

        // counted drain: tile j+1 landed; keep tile j+2's 4 loads in flight
        if (j <= NKT - 3)      { WAIT_VM4(); }
        else if (j == NKT - 2) { WAIT_VM0(); }
        BAR();
    }

    // epilogue: lane (k8,l15) of frag (nf,mf) holds out-cols
    // bn + wn*64 + nf*16 + k8*4 + {0..3} of node bm + wm*64 + mf*16 + l15
    const int node0 = bm + wm * 64 + l15;
    const int colg = bn + wn * 64 + k8 * 4;
    float4 bv[4];
#pragma unroll
    for (int nf = 0; nf < 4; ++nf)
        bv[nf] = *(const float4*)(bias + colg + nf * 16);

#pragma unroll
    for (int mf = 0; mf < 4; ++mf) {
        const int node = node0 + mf * 16;
        if (node < M) {
            float v[4][4];
#pragma unroll
            for (int nf = 0; nf < 4; ++nf) {
                v[nf][0] = acc[nf][mf][0] + bv[nf].x;
                v[nf][1] = acc[nf][mf][1] + bv[nf].y;
                v[nf][2] = acc[nf][mf][2] + bv[nf].z;
                v[nf][3] = acc[nf][mf][3] + bv[nf].w;
                if (relu) {
#pragma unroll
                    for (int t = 0; t < 4; ++t) v[nf][t] = fmaxf(v[nf][t], 0.f);
                }
            }
            if (Xn) {
                uint2* rowp = (uint2*)(Xn + (size_t)node * D + colg);
#pragma unroll
                for (int nf = 0; nf < 4; ++nf) {
                    uint2 o2;
                    o2.x = pack2(v[nf][0], v[nf][1]);
                    o2.y = pack2(v[nf][2], v[nf][3]);
                    rowp[nf * 4] = o2;         // nf*16 cols = 4 uint2
                }
            } else {
                float4* rowp = (float4*)(outf + (size_t)node * D + colg);
#pragma unroll
                for (int nf = 0; nf < 4; ++nf)
                    rowp[nf * 4] = make_float4(v[nf][0], v[nf][1],
                                               v[nf][2], v[nf][3]);
            }
        }
    }
}

// ---- preprocessing: CSR by (rel, dst) ----

__global__ __launch_bounds__(256) void count_edges(
    const int* __restrict__ dst, const int* __restrict__ et,
    int* __restrict__ cntI, int E, int M)
{
    const int e = blockIdx.x * blockDim.x + threadIdx.x;
    if (e < E) atomicAdd(&cntI[(size_t)et[e] * M + dst[e]], 1);
}

// ---- 3-kernel hierarchical exclusive scan (n ~ 100k) ----
// scan_local also: invc[i] = 1/max(hist,1) and zeroes hist (cursor reuse),
// replacing the old finalize_cnt kernel + second memset.
__global__ __launch_bounds__(1024) void scan_local(
    int* __restrict__ hist, int* __restrict__ offs,
    int* __restrict__ bsums, float* __restrict__ invc, int n)
{
    __shared__ int tmp[1024];
    const int tid = threadIdx.x;
    const int i = blockIdx.x * 1024 + tid;
    const int v = (i < n) ? hist[i] : 0;
    if (i < n) {
        invc[i] = 1.0f / (float)max(v, 1);
        hist[i] = 0;                    // pre-zero cursor for fill_sorted
    }
    tmp[tid] = v;
    __syncthreads();
#pragma unroll
    for (int off = 1; off < 1024; off <<= 1) {
        const int add = (tid >= off) ? tmp[tid - off] : 0;
        __syncthreads();
        tmp[tid] += add;
        __syncthreads();
    }
    if (i < n) offs[i] = tmp[tid] - v;
    if (tid == 1023) bsums[blockIdx.x] = tmp[1023];
}

__global__ __launch_bounds__(1024) void scan_bsums(
    int* __restrict__ bsums, int* __restrict__ total_out, int nb)
{
    __shared__ int tmp[1024];
    const int tid = threadIdx.x;
    const int v = (tid < nb) ? bsums[tid] : 0;
    tmp[tid] = v;
    __syncthreads();
#pragma unroll
    for (int off = 1; off < 1024; off <<= 1) {
        const int add = (tid >= off) ? tmp[tid - off] : 0;
        __syncthreads();
        tmp[tid] += add;
        __syncthreads();
    }
    if (tid < nb) bsums[tid] = tmp[tid] - v;
    if (tid == 1023) *total_out = tmp[1023];
}

__global__ __launch_bounds__(1024) void scan_add(
    int* __restrict__ offs, const int* __restrict__ bsums, int n)
{
    const int i = blockIdx.x * 1024 + threadIdx.x;
    if (i < n) offs[i] += bsums[blockIdx.x];
}

__global__ __launch_bounds__(256) void fill_sorted(
    const int* __restrict__ src, const int* __restrict__ dst,
    const int* __restrict__ et, const int* __restrict__ offs,
    int* __restrict__ cursor, int* __restrict__ sorted, int E, int M)
{
    const int e = blockIdx.x * blockDim.x + threadIdx.x;
    if (e < E) {
        const int key = et[e] * M + dst[e];
        const int pos = offs[key] + atomicAdd(&cursor[key], 1);
        sorted[pos] = src[e];
    }
}

// ---- weights -> BT bf16 [384 n-rows][1152 k-cols] per layer ----
// BT[n][k] = Wcat[k][n]; k<384: root, k<768: W[0], else W[1].
__global__ __launch_bounds__(256) void build_bt(
    const float* __restrict__ root1, const float* __restrict__ W1,
    const float* __restrict__ root2, const float* __restrict__ W2,
    const float* __restrict__ root3, const float* __restrict__ W3,
    ushort* __restrict__ BT)
{
    __shared__ float tile[32][33];
    const int l = blockIdx.z;
    const float* root = (l == 0) ? root1 : (l == 1) ? root2 : root3;
    const float* W    = (l == 0) ? W1    : (l == 1) ? W2    : W3;
    const int k0 = blockIdx.x * 32;   // K block (0..1151)
    const int n0 = blockIdx.y * 32;   // N block (0..383)
    const int tx = threadIdx.x & 31;
    const int ty = threadIdx.x >> 5;
    const float* srcm;
    int koff;
    if (k0 < D)          { srcm = root;      koff = 0; }
    else if (k0 < 2 * D) { srcm = W;         koff = D; }
    else                 { srcm = W + D * D; koff = 2 * D; }
#pragma unroll
    for (int i = 0; i < 4; ++i) {
        const int k = k0 - koff + ty + i * 8;
        tile[ty + i * 8][tx] = srcm[(size_t)k * D + n0 + tx];
    }
    __syncthreads();
    ushort* dst = BT + (size_t)l * D * KC;
#pragma unroll
    for (int i = 0; i < 4; ++i) {
        const int nn = n0 + ty + i * 8;
        const int kk = k0 + tx;
        dst[(size_t)nn * KC + kk] = f2bf(tile[tx][ty + i * 8]);
    }
}

__global__ __launch_bounds__(256) void cast_f32_to_bf16(
    const float* __restrict__ x, ushort* __restrict__ y, int n4)
{
    const int i = blockIdx.x * blockDim.x + threadIdx.x;
    if (i < n4) {
        const float4 v = ((const float4*)x)[i];
        uint2 o;
        o.x = pack2(v.x, v.y);
        o.y = pack2(v.z, v.w);
        ((uint2*)y)[i] = o;
    }
}

// ---- relation aggregation: one wave per (node, rel) ----
// key = r*M + d (matches offs/invc layout). Edge indices loaded
// lane-parallel (one coalesced load per 64 edges) and broadcast via __shfl;
// gather loop unrolled x2 so two 768 B source rows are in flight.
// Writes AG[d][r*384 + :] bf16.
__global__ __launch_bounds__(256) void aggregate_rel(
    const ushort* __restrict__ X, const int* __restrict__ sorted,
    const int* __restrict__ offs, const float* __restrict__ invc,
    ushort* __restrict__ AG, int M)
{
    const int wave = threadIdx.x >> 6;
    const int lane = threadIdx.x & 63;
    const int key = blockIdx.x * 4 + wave;   // 0 .. 2M-1
    if (key >= 2 * M) return;
    const int r = (key >= M) ? 1 : 0;
    const int d = key - r * M;

    const int beg = offs[key], end = offs[key + 1];
    float g0 = 0.f, g1 = 0.f, g2 = 0.f, g3 = 0.f, g4 = 0.f, g5 = 0.f;

    for (int base = beg; base < end; base += 64) {
        const int cnt = min(end - base, 64);
        const int idx = (lane < cnt) ? sorted[base + lane] : 0;
        int e = 0;
        for (; e + 2 <= cnt; e += 2) {
            const int s0 = __shfl(idx, e);
            const int s1 = __shfl(idx, e + 1);
            const uint* t0 = (const uint*)(X + (size_t)s0 * D);
            const uint* t1 = (const uint*)(X + (size_t)s1 * D);
            const uint a0 = t0[lane], a1 = t0[lane + 64], a2 = t0[lane + 128];
            const uint b0 = t1[lane], b1 = t1[lane + 64], b2 = t1[lane + 128];
            g0 += __uint_as_float(a0 << 16) + __uint_as_float(b0 << 16);
            g1 += __uint_as_float(a0 & 0xffff0000u) + __uint_as_float(b0 & 0xffff0000u);
            g2 += __uint_as_float(a1 << 16) + __uint_as_float(b1 << 16);
            g3 += __uint_as_float(a1 & 0xffff0000u) + __uint_as_float(b1 & 0xffff0000u);
            g4 += __uint_as_float(a2 << 16) + __uint_as_float(b2 << 16);
            g5 += __uint_as_float(a2 & 0xffff0000u) + __uint_as_float(b2 & 0xffff0000u);
        }
        if (e < cnt) {
            const int s0 = __shfl(idx, e);
            const uint* t0 = (const uint*)(X + (size_t)s0 * D);
            const uint a0 = t0[lane], a1 = t0[lane + 64], a2 = t0[lane + 128];
            g0 += __uint_as_float(a0 << 16);
            g1 += __uint_as_float(a0 & 0xffff0000u);
            g2 += __uint_as_float(a1 << 16);
            g3 += __uint_as_float(a1 & 0xffff0000u);
            g4 += __uint_as_float(a2 << 16);
            g5 += __uint_as_float(a2 & 0xffff0000u);
        }
    }

    const float ic = invc[key];
    uint* op = (uint*)(AG + (size_t)d * (2 * D) + r * D);
    op[lane]       = pack2(ic * g0, ic * g1);
    op[lane + 64]  = pack2(ic * g2, ic * g3);
    op[lane + 128] = pack2(ic * g4, ic * g5);
}

extern "C" void kernel_launch(void* const* d_in, const int* in_sizes, int n_in,
                              void* d_out, int out_size, void* d_ws, size_t ws_size,
                              hipStream_t stream)
{
    const float* emb   = (const float*)d_in[0];
    const int*   eidx  = (const int*)d_in[1];
    const int*   et    = (const int*)d_in[2];
    const float* W1    = (const float*)d_in[3];
    const float* root1 = (const float*)d_in[4];
    const float* bias1 = (const float*)d_in[5];
    const float* W2    = (const float*)d_in[6];
    const float* root2 = (const float*)d_in[7];
    const float* bias2 = (const float*)d_in[8];
    const float* W3    = (const float*)d_in[9];
    const float* root3 = (const float*)d_in[10];
    const float* bias3 = (const float*)d_in[11];

    float* out = (float*)d_out;
    const int M = in_sizes[0] / D;   // 50000
    const int E = in_sizes[1] / 2;   // 200000
    const int* src  = eidx;
    const int* dstv = eidx + E;

    const int n = 2 * M;
    const int nb = (n + 1023) / 1024;

    // Workspace: Xa[M*384]bf16 | Xb2[M*384]bf16 | AG[M*768]bf16 |
    //            BT[3*384*1152]bf16 | invcnt[2M]f32 | cntI[2M]i32 |
    //            offs[2M+1]i32 | sorted[E]i32 | bsums[nb]i32   (~158 MB)
    char* w = (char*)d_ws;
    ushort* Xa  = (ushort*)w;         w += (size_t)M * D * 2;
    ushort* Xb2 = (ushort*)w;         w += (size_t)M * D * 2;
    ushort* AG  = (ushort*)w;         w += (size_t)M * 2 * D * 2;
    ushort* BT  = (ushort*)w;         w += (size_t)3 * D * KC * 2;
    float* invcnt = (float*)w;        w += (size_t)n * 4;
    int* cntI = (int*)w;              w += (size_t)n * 4;
    int* offs = (int*)w;              w += ((size_t)n + 1) * 4;
    int* sorted = (int*)w;            w += (size_t)E * 4;
    int* bsums = (int*)w;

    // --- preprocessing (14 dispatches total incl. 3x(agg+gemm)) ---
    hipMemsetAsync(cntI, 0, (size_t)n * sizeof(int), stream);
    count_edges<<<(E + 255) / 256, 256, 0, stream>>>(dstv, et, cntI, E, M);
    scan_local<<<nb, 1024, 0, stream>>>(cntI, offs, bsums, invcnt, n);
    scan_bsums<<<1, 1024, 0, stream>>>(bsums, offs + n, nb);
    scan_add<<<nb, 1024, 0, stream>>>(offs, bsums, n);
    fill_sorted<<<(E + 255) / 256, 256, 0, stream>>>(src, dstv, et, offs, cntI, sorted, E, M);

    build_bt<<<dim3(KC / 32, D / 32, 3), 256, 0, stream>>>(root1, W1, root2, W2, root3, W3, BT);
    cast_f32_to_bf16<<<(M * D / 4 + 255) / 256, 256, 0, stream>>>(emb, Xa, M * D / 4);

    // GEMM grid: 391 M-tiles x 3 N-tiles, bijective XCD swizzle in-kernel
    const int Mtiles = (M + BM - 1) / BM;
    const int nwg = Mtiles * NTN;
    const int agg_blocks = (2 * M + 3) / 4;   // one wave per (node, rel)

    // Layer 1: X = Xa -> Xb2
    aggregate_rel<<<agg_blocks, 256, 0, stream>>>(Xa, sorted, offs, invcnt, AG, M);
    gemm_fused<<<nwg, 256, 0, stream>>>(Xa, AG, BT, bias1, Xb2, nullptr, M, nwg, 1);
    // Layer 2: Xb2 -> Xa
    aggregate_rel<<<agg_blocks, 256, 0, stream>>>(Xb2, sorted, offs, invcnt, AG, M);
    gemm_fused<<<nwg, 256, 0, stream>>>(Xb2, AG, BT + (size_t)D * KC, bias2, Xa, nullptr, M, nwg, 1);
    // Layer 3: Xa -> out (f32, no relu)
    aggregate_rel<<<agg_blocks, 256, 0, stream>>>(Xa, sorted, offs, invcnt, AG, M);
    gemm_fused<<<nwg, 256, 0, stream>>>(Xa, AG, BT + (size_t)2 * D * KC, bias3, nullptr, out, M, nwg, 0);
}